// Round 2
// baseline (1229.137 us; speedup 1.0000x reference)
//
#include <hip/hip_runtime.h>
#include <hip/hip_bf16.h>

typedef __attribute__((ext_vector_type(8))) short short8;
typedef __attribute__((ext_vector_type(4))) float f32x4;

typedef __attribute__((address_space(1))) const void GV;
typedef __attribute__((address_space(3))) void LV;

__device__ __forceinline__ unsigned short f2bf(float f) {
  union { float f; unsigned u; } v; v.f = f;
  unsigned r = v.u + 0x7fffu + ((v.u >> 16) & 1u);
  return (unsigned short)(r >> 16);
}
__device__ __forceinline__ float bf2f(unsigned short s) {
  union { unsigned u; float f; } v; v.u = ((unsigned)s) << 16;
  return v.f;
}

// ---------------- weight f32 -> bf16 ----------------
__global__ __launch_bounds__(256) void convert_weights(
    const float* __restrict__ w1, const float* __restrict__ w2, const float* __restrict__ w3,
    unsigned short* __restrict__ w1b, unsigned short* __restrict__ w2b, unsigned short* __restrict__ w3b) {
  int i = blockIdx.x * 256 + threadIdx.x;
  if (i < 524288) w1b[i] = f2bf(w1[i]);
  if (i < 131072) w2b[i] = f2bf(w2[i]);
  if (i < 32768)  w3b[i] = f2bf(w3[i]);
}

// ---------------- x (B,1024,256) f32 -> xT (B,256,1024) bf16 ----------------
__global__ __launch_bounds__(256) void transpose_x(const float* __restrict__ x,
                                                   unsigned short* __restrict__ xT) {
  __shared__ float tile[64][65];
  int bid = blockIdx.x;
  int nt = bid & 3, ct = (bid >> 2) & 15, b = bid >> 6;
  int c0 = ct << 6, n0 = nt << 6;
  int tx = threadIdx.x & 63, ty = threadIdx.x >> 6;
  const float* xp = x + ((size_t)b * 1024 + c0) * 256 + n0;
  #pragma unroll
  for (int r = ty; r < 64; r += 4) tile[r][tx] = xp[(size_t)r * 256 + tx];
  __syncthreads();
  unsigned short* op = xT + ((size_t)b * 256 + n0) * 1024 + c0;
  int cc = (threadIdx.x & 31) * 2;
  #pragma unroll
  for (int rn = threadIdx.x >> 5; rn < 64; rn += 8) {
    ushort2 o2; o2.x = f2bf(tile[cc][rn]); o2.y = f2bf(tile[cc + 1][rn]);
    *reinterpret_cast<ushort2*>(op + (size_t)rn * 1024 + cc) = o2;
  }
}

// ---------------- batched GEMM + BN-stat accumulation ----------------
// W: (M,K) bf16 row-major.  X: (B,256,K) bf16 (K contiguous).  Y: (B,256,M) bf16.
// stat: (M,2) f32 pre-zeroed: sum, sumsq of y over (b,n).
template<int M, int K>
__global__ __launch_bounds__(256, 2) void gemm_bn(
    const unsigned short* __restrict__ W, const unsigned short* __restrict__ X,
    unsigned short* __restrict__ Y, float* __restrict__ stat) {
  constexpr int NMT = M / 128;
  __shared__ unsigned short As[128 * 32];
  __shared__ unsigned short Bs[128 * 32];
  __shared__ float bsum[128], bsq[128];

  int tid = threadIdx.x, bid = blockIdx.x;
  int nt = bid & 1;
  int mt = (bid >> 1) % NMT;
  int b  = bid / (2 * NMT);
  int wid = tid >> 6, lane = tid & 63;
  int wr = wid >> 1, wc = wid & 1;
  int m0 = mt * 128, n0 = nt * 128;

  if (tid < 128) { bsum[tid] = 0.f; bsq[tid] = 0.f; }

  const unsigned short* Ag = W + (size_t)m0 * K;
  const unsigned short* Bg = X + ((size_t)b * 256 + n0) * K;

  int cA = wid * 64 + lane;
  int rowA = cA >> 2, colA = (cA & 3) * 8;

  f32x4 acc[4][4];
  #pragma unroll
  for (int i = 0; i < 4; ++i)
    #pragma unroll
    for (int j = 0; j < 4; ++j)
      #pragma unroll
      for (int r = 0; r < 4; ++r) acc[i][j][r] = 0.f;

  char* AsW = (char*)As + wid * 1024;
  char* BsW = (char*)Bs + wid * 1024;
  int lrow = lane & 15, lk = (lane >> 4) * 16;

  for (int kt = 0; kt < K / 32; ++kt) {
    int k0 = kt * 32;
    __syncthreads();
    __builtin_amdgcn_global_load_lds((GV*)(Ag + (size_t)rowA * K + k0 + colA), (LV*)AsW, 16, 0, 0);
    __builtin_amdgcn_global_load_lds((GV*)(Ag + (size_t)(rowA + 64) * K + k0 + colA), (LV*)(AsW + 4096), 16, 0, 0);
    __builtin_amdgcn_global_load_lds((GV*)(Bg + (size_t)rowA * K + k0 + colA), (LV*)BsW, 16, 0, 0);
    __builtin_amdgcn_global_load_lds((GV*)(Bg + (size_t)(rowA + 64) * K + k0 + colA), (LV*)(BsW + 4096), 16, 0, 0);
    __syncthreads();
    short8 af[4], bfv[4];
    #pragma unroll
    for (int i = 0; i < 4; ++i) {
      af[i]  = *reinterpret_cast<const short8*>((const char*)As + (wr * 64 + i * 16 + lrow) * 64 + lk);
      bfv[i] = *reinterpret_cast<const short8*>((const char*)Bs + (wc * 64 + i * 16 + lrow) * 64 + lk);
    }
    #pragma unroll
    for (int i = 0; i < 4; ++i)
      #pragma unroll
      for (int j = 0; j < 4; ++j)
        acc[i][j] = __builtin_amdgcn_mfma_f32_16x16x32_bf16(af[i], bfv[j], acc[i][j], 0, 0, 0);
  }

  // epilogue: store Y (b,n,o) — each lane stores 4 consecutive o (m89 C/D mapping)
  size_t ybase = (size_t)b * 256 * M;
  int group = lane >> 4;
  #pragma unroll
  for (int mi = 0; mi < 4; ++mi) {
    int o0 = m0 + wr * 64 + mi * 16 + group * 4;
    #pragma unroll
    for (int ni = 0; ni < 4; ++ni) {
      int n = n0 + wc * 64 + ni * 16 + lrow;
      ushort4 pk;
      pk.x = f2bf(acc[mi][ni][0]);
      pk.y = f2bf(acc[mi][ni][1]);
      pk.z = f2bf(acc[mi][ni][2]);
      pk.w = f2bf(acc[mi][ni][3]);
      *reinterpret_cast<ushort4*>(Y + ybase + (size_t)n * M + o0) = pk;
    }
  }
  // stats (f32, pre-rounding)
  #pragma unroll
  for (int mi = 0; mi < 4; ++mi) {
    #pragma unroll
    for (int r = 0; r < 4; ++r) {
      float s = 0.f, q = 0.f;
      #pragma unroll
      for (int ni = 0; ni < 4; ++ni) { float v = acc[mi][ni][r]; s += v; q += v * v; }
      #pragma unroll
      for (int msk = 1; msk < 16; msk <<= 1) {
        s += __shfl_xor(s, msk, 64);
        q += __shfl_xor(q, msk, 64);
      }
      if (lrow == 0) {
        int ol = wr * 64 + mi * 16 + group * 4 + r;
        atomicAdd(&bsum[ol], s);
        atomicAdd(&bsq[ol], q);
      }
    }
  }
  __syncthreads();
  if (tid < 128) {
    atomicAdd(&stat[(m0 + tid) * 2],     bsum[tid]);
    atomicAdd(&stat[(m0 + tid) * 2 + 1], bsq[tid]);
  }
}

// ---------------- BN finalize: a = g*rstd, c = be - a*mean ----------------
template<int M>
__global__ void finalize_stats(const float* __restrict__ stat, const float* __restrict__ g,
                               const float* __restrict__ be, float* __restrict__ aArr,
                               float* __restrict__ cArr) {
  int i = blockIdx.x * 64 + threadIdx.x;
  if (i >= M) return;
  const float inv = 1.0f / 131072.0f;  // B*N = 512*256
  float mean = stat[2 * i] * inv;
  float var  = stat[2 * i + 1] * inv - mean * mean;
  float rstd = rsqrtf(var + 1e-5f);
  float a = g[i] * rstd;
  aArr[i] = a;
  cArr[i] = be[i] - a * mean;
}

// ---------------- elementwise BN + ReLU (in-place, bf16x8) ----------------
template<int M>
__global__ __launch_bounds__(256) void bn_relu(unsigned short* __restrict__ Y,
                                               const float* __restrict__ aArr,
                                               const float* __restrict__ cArr) {
  int idx = blockIdx.x * 256 + threadIdx.x;
  int o0 = (idx % (M / 8)) * 8;
  uint4 u = *reinterpret_cast<const uint4*>(Y + (size_t)idx * 8);
  float4 a0 = *reinterpret_cast<const float4*>(aArr + o0);
  float4 a1 = *reinterpret_cast<const float4*>(aArr + o0 + 4);
  float4 c0 = *reinterpret_cast<const float4*>(cArr + o0);
  float4 c1 = *reinterpret_cast<const float4*>(cArr + o0 + 4);
  const unsigned short* pu = reinterpret_cast<const unsigned short*>(&u);
  float va[8] = {a0.x, a0.y, a0.z, a0.w, a1.x, a1.y, a1.z, a1.w};
  float vc[8] = {c0.x, c0.y, c0.z, c0.w, c1.x, c1.y, c1.z, c1.w};
  uint4 outv;
  unsigned short* po = reinterpret_cast<unsigned short*>(&outv);
  #pragma unroll
  for (int j = 0; j < 8; ++j) {
    float h = fmaxf(va[j] * bf2f(pu[j]) + vc[j], 0.f);
    po[j] = f2bf(h);
  }
  *reinterpret_cast<uint4*>(Y + (size_t)idx * 8) = outv;
}

// ---------------- layer4 + sigmoid + WLS fit ----------------
__global__ __launch_bounds__(256) void final_fit(
    const unsigned short* __restrict__ H,   // (B,256,128) bf16
    const float* __restrict__ w4, const float* __restrict__ b4,
    const float* __restrict__ points,       // (B,3,256)
    float* __restrict__ out) {              // normal[1536] | beta[1536] | weights[131072]
  int b = blockIdx.x, n = threadIdx.x;
  __shared__ float w4s[128];
  __shared__ float red[4][9];
  if (n < 128) w4s[n] = w4[n];
  __syncthreads();

  const unsigned short* h = H + ((size_t)b * 256 + n) * 128;
  float logit = b4[0];
  #pragma unroll
  for (int i = 0; i < 16; ++i) {
    uint4 u = *reinterpret_cast<const uint4*>(h + i * 8);
    const unsigned short* pu = reinterpret_cast<const unsigned short*>(&u);
    #pragma unroll
    for (int j = 0; j < 8; ++j) logit += w4s[i * 8 + j] * bf2f(pu[j]);
  }
  float wgt = 0.01f + 1.0f / (1.0f + expf(-logit));
  out[3072 + b * 256 + n] = wgt;

  const float* p = points + (size_t)b * 768;
  float px = p[n], py = p[256 + n], pz = p[512 + n];
  float v[9] = {wgt * px * px, wgt * px * py, wgt * px, wgt * py * py, wgt * py,
                wgt, wgt * px * pz, wgt * py * pz, wgt * pz};
  #pragma unroll
  for (int k = 0; k < 9; ++k)
    #pragma unroll
    for (int msk = 1; msk < 64; msk <<= 1) v[k] += __shfl_xor(v[k], msk, 64);
  int wid = n >> 6, lane = n & 63;
  if (lane == 0)
    #pragma unroll
    for (int k = 0; k < 9; ++k) red[wid][k] = v[k];
  __syncthreads();
  if (n == 0) {
    double S[9];
    #pragma unroll
    for (int k = 0; k < 9; ++k)
      S[k] = (double)red[0][k] + red[1][k] + red[2][k] + red[3][k];
    double a11 = S[0], a12 = S[1], a13 = S[2], a22 = S[3], a23 = S[4], a33 = S[5];
    double t1 = S[6], t2 = S[7], t3 = S[8];
    double d  = a11 * (a22 * a33 - a23 * a23) - a12 * (a12 * a33 - a23 * a13) + a13 * (a12 * a23 - a22 * a13);
    double b0 = (t1 * (a22 * a33 - a23 * a23) - a12 * (t2 * a33 - a23 * t3) + a13 * (t2 * a23 - a22 * t3)) / d;
    double b1 = (a11 * (t2 * a33 - t3 * a23) - t1 * (a12 * a33 - a23 * a13) + a13 * (a12 * t3 - t2 * a13)) / d;
    double b2 = (a11 * (a22 * t3 - a23 * t2) - a12 * (a12 * t3 - t2 * a13) + t1 * (a12 * a23 - a13 * a22)) / d;
    double nn = sqrt(b0 * b0 + b1 * b1 + 1.0);
    out[b * 3 + 0] = (float)(-b0 / nn);
    out[b * 3 + 1] = (float)(-b1 / nn);
    out[b * 3 + 2] = (float)(1.0 / nn);
    out[1536 + b * 3 + 0] = (float)b0;
    out[1536 + b * 3 + 1] = (float)b1;
    out[1536 + b * 3 + 2] = (float)b2;
  }
}

extern "C" void kernel_launch(void* const* d_in, const int* in_sizes, int n_in,
                              void* d_out, int out_size, void* d_ws, size_t ws_size,
                              hipStream_t stream) {
  const float* points = (const float*)d_in[0];
  const float* x   = (const float*)d_in[1];
  const float* w1  = (const float*)d_in[3];
  const float* g1  = (const float*)d_in[5];
  const float* be1 = (const float*)d_in[6];
  const float* w2  = (const float*)d_in[7];
  const float* g2  = (const float*)d_in[9];
  const float* be2 = (const float*)d_in[10];
  const float* w3  = (const float*)d_in[11];
  const float* g3  = (const float*)d_in[13];
  const float* be3 = (const float*)d_in[14];
  const float* w4  = (const float*)d_in[15];
  const float* b4  = (const float*)d_in[16];
  float* out = (float*)d_out;

  char* ws = (char*)d_ws;
  // region A (reused): xT (256MB) -> later y2 (64MB) + y3 (32MB)
  unsigned short* xT  = (unsigned short*)(ws);
  unsigned short* y2  = (unsigned short*)(ws);
  unsigned short* y3  = (unsigned short*)(ws + 67108864);
  unsigned short* y1  = (unsigned short*)(ws + 268435456);   // 128MB
  unsigned short* w1b = (unsigned short*)(ws + 402653184);
  unsigned short* w2b = (unsigned short*)(ws + 403701760);
  unsigned short* w3b = (unsigned short*)(ws + 403963904);
  float* stat1 = (float*)(ws + 404029440);        // 512*2
  float* stat2 = stat1 + 1024;                    // 256*2
  float* stat3 = stat2 + 512;                     // 128*2
  float* a1 = stat3 + 256; float* c1 = a1 + 512;
  float* a2 = c1 + 512;    float* c2 = a2 + 256;
  float* a3 = c2 + 256;    float* c3 = a3 + 128;

  hipMemsetAsync(stat1, 0, (1024 + 512 + 256) * sizeof(float), stream);
  convert_weights<<<2048, 256, 0, stream>>>(w1, w2, w3, w1b, w2b, w3b);
  transpose_x<<<32768, 256, 0, stream>>>(x, xT);

  gemm_bn<512, 1024><<<4096, 256, 0, stream>>>(w1b, xT, y1, stat1);
  finalize_stats<512><<<8, 64, 0, stream>>>(stat1, g1, be1, a1, c1);
  bn_relu<512><<<32768, 256, 0, stream>>>(y1, a1, c1);

  gemm_bn<256, 512><<<2048, 256, 0, stream>>>(w2b, y1, y2, stat2);
  finalize_stats<256><<<4, 64, 0, stream>>>(stat2, g2, be2, a2, c2);
  bn_relu<256><<<16384, 256, 0, stream>>>(y2, a2, c2);

  gemm_bn<128, 256><<<1024, 256, 0, stream>>>(w3b, y2, y3, stat3);
  finalize_stats<128><<<2, 64, 0, stream>>>(stat3, g3, be3, a3, c3);
  bn_relu<128><<<8192, 256, 0, stream>>>(y3, a3, c3);

  final_fit<<<512, 256, 0, stream>>>(y3, w4, b4, points, out);
}